// Round 1
// baseline (435.216 us; speedup 1.0000x reference)
//
#include <hip/hip_runtime.h>
#include <hip/hip_bf16.h>

#define NROWS 16384
#define DIM   1024

typedef __bf16 bf16x8 __attribute__((ext_vector_type(8)));
typedef __bf16 bf16x4 __attribute__((ext_vector_type(4)));
typedef float  f32x4  __attribute__((ext_vector_type(4)));

// monotone float -> uint key (order-preserving), so atomicMax works on floats
__device__ __forceinline__ unsigned fkey(float f) {
    unsigned u = __float_as_uint(f);
    return (u & 0x80000000u) ? ~u : (u | 0x80000000u);
}
__device__ __forceinline__ float funkey(unsigned k) {
    unsigned u = (k & 0x80000000u) ? (k & 0x7fffffffu) : ~k;
    return __uint_as_float(u);
}

// One block per row: fp32 sum-of-squares, scale, emit bf16 row. Also init rowmax.
__global__ void normalize_rows(const float* __restrict__ x,
                               __hip_bfloat16* __restrict__ xn,
                               unsigned* __restrict__ rowmax) {
    const int row = blockIdx.x;
    const int t = threadIdx.x;                      // 256 threads, 1 float4 each
    const float4 v = ((const float4*)(x + (size_t)row * DIM))[t];
    float ss = v.x * v.x + v.y * v.y + v.z * v.z + v.w * v.w;
#pragma unroll
    for (int off = 32; off > 0; off >>= 1) ss += __shfl_xor(ss, off);
    __shared__ float wss[4];
    if ((t & 63) == 0) wss[t >> 6] = ss;
    __syncthreads();
    const float tot = wss[0] + wss[1] + wss[2] + wss[3];
    const float scale = 1.0f / fmaxf(sqrtf(tot), 1e-12f);
    bf16x4 o;
    o[0] = (__bf16)(v.x * scale);
    o[1] = (__bf16)(v.y * scale);
    o[2] = (__bf16)(v.z * scale);
    o[3] = (__bf16)(v.w * scale);
    *(bf16x4*)(xn + (size_t)row * DIM + t * 4) = o;
    if (t == 0) rowmax[row] = 0u;                   // below fkey of any real sim
}

// 128x128 tile of sim = xn * xn^T (both operands are rows of xn, K-contiguous).
// Upper-triangle tiles only (jt >= it); each tile reduces to per-row and
// per-col maxes and atomicMax'es them into rowmax (symmetry gives cols).
__global__ void simmax_kernel(const __hip_bfloat16* __restrict__ xn,
                              unsigned* __restrict__ rowmax) {
    const int jt = blockIdx.x;            // col tile
    const int it = blockIdx.y;            // row tile
    if (jt < it) return;                  // symmetry: skip lower triangle
    const bool diag = (jt == it);
    const int rowBase = it * 128;
    const int colBase = jt * 128;

    __shared__ __hip_bfloat16 As[128 * 64];
    __shared__ __hip_bfloat16 Bs[128 * 64];

    const int t    = threadIdx.x;         // 256 = 4 waves
    const int lane = t & 63;
    const int wid  = t >> 6;
    const int wr   = wid >> 1;            // 2x2 wave grid, each wave 64x64
    const int wc   = wid & 1;

    f32x4 acc[4][4];
#pragma unroll
    for (int m = 0; m < 4; ++m)
#pragma unroll
        for (int n = 0; n < 4; ++n)
            acc[m][n] = (f32x4){0.f, 0.f, 0.f, 0.f};

    // staging: each lane loads 16B (8 bf16); 8 lanes cover one 64-elem k-row
    const int srow  = wid * 8 + (lane >> 3);
    const int skcol = (lane & 7) * 8;

    for (int kt = 0; kt < DIM; kt += 64) {
        __syncthreads();                  // previous compute done before overwrite
#pragma unroll
        for (int is = 0; is < 4; ++is) {
            const int r = is * 32 + srow;
            const __hip_bfloat16* ga = xn + (size_t)(rowBase + r) * DIM + kt + skcol;
            const __hip_bfloat16* gb = xn + (size_t)(colBase + r) * DIM + kt + skcol;
            __hip_bfloat16* la = As + (is * 32 + wid * 8) * 64;   // wave-uniform base
            __hip_bfloat16* lb = Bs + (is * 32 + wid * 8) * 64;
            __builtin_amdgcn_global_load_lds((const __attribute__((address_space(1))) void*)ga,
                                             (__attribute__((address_space(3))) void*)la, 16, 0, 0);
            __builtin_amdgcn_global_load_lds((const __attribute__((address_space(1))) void*)gb,
                                             (__attribute__((address_space(3))) void*)lb, 16, 0, 0);
        }
        __syncthreads();                  // compiler drains vmcnt before barrier
#pragma unroll
        for (int kk = 0; kk < 64; kk += 32) {
            bf16x8 af[4], bfr[4];
            const int arow0 = wr * 64 + (lane & 15);
            const int brow0 = wc * 64 + (lane & 15);
            const int kof   = kk + (lane >> 4) * 8;
#pragma unroll
            for (int m = 0; m < 4; ++m)
                af[m] = *(const bf16x8*)(As + (arow0 + m * 16) * 64 + kof);
#pragma unroll
            for (int n = 0; n < 4; ++n)
                bfr[n] = *(const bf16x8*)(Bs + (brow0 + n * 16) * 64 + kof);
#pragma unroll
            for (int m = 0; m < 4; ++m)
#pragma unroll
                for (int n = 0; n < 4; ++n)
                    acc[m][n] = __builtin_amdgcn_mfma_f32_16x16x32_bf16(af[m], bfr[n], acc[m][n], 0, 0, 0);
        }
    }

    // C/D layout: col = lane&15, row = (lane>>4)*4 + reg   [m89/m91 verified]
    const int g  = lane >> 4;
    const int cl = lane & 15;

    // row-direction max (max over tile cols for each tile row)
    float rm[4][4];
#pragma unroll
    for (int m = 0; m < 4; ++m) {
#pragma unroll
        for (int r = 0; r < 4; ++r) {
            float v = -3.0f;
#pragma unroll
            for (int n = 0; n < 4; ++n) {
                float a = acc[m][n][r];
                if (diag) {
                    const int grow = wr * 64 + m * 16 + g * 4 + r;
                    const int gcol = wc * 64 + n * 16 + cl;
                    if (grow == gcol) a = -3.0f;   // exclude self-similarity
                }
                v = fmaxf(v, a);
            }
            rm[m][r] = v;
        }
    }
#pragma unroll
    for (int m = 0; m < 4; ++m)
#pragma unroll
        for (int r = 0; r < 4; ++r) {
            float v = rm[m][r];
            v = fmaxf(v, __shfl_xor(v, 1));
            v = fmaxf(v, __shfl_xor(v, 2));
            v = fmaxf(v, __shfl_xor(v, 4));
            v = fmaxf(v, __shfl_xor(v, 8));
            rm[m][r] = v;
        }
    if (cl == 0) {
#pragma unroll
        for (int m = 0; m < 4; ++m)
#pragma unroll
            for (int r = 0; r < 4; ++r) {
                const int grow = rowBase + wr * 64 + m * 16 + g * 4 + r;
                atomicMax(rowmax + grow, fkey(rm[m][r]));
            }
    }

    // col-direction max (transpose contribution), skip on diagonal tiles
    if (!diag) {
        float cm[4];
#pragma unroll
        for (int n = 0; n < 4; ++n) {
            float v = -3.0f;
#pragma unroll
            for (int m = 0; m < 4; ++m)
#pragma unroll
                for (int r = 0; r < 4; ++r)
                    v = fmaxf(v, acc[m][n][r]);
            v = fmaxf(v, __shfl_xor(v, 16));
            v = fmaxf(v, __shfl_xor(v, 32));
            cm[n] = v;
        }
        if (g == 0) {
#pragma unroll
            for (int n = 0; n < 4; ++n) {
                const int gcol = colBase + wc * 64 + n * 16 + cl;
                atomicMax(rowmax + gcol, fkey(cm[n]));
            }
        }
    }
}

__global__ void finalize_kernel(const unsigned* __restrict__ rowmax,
                                float* __restrict__ out) {
    const int t = threadIdx.x;            // 256 threads, 1 block
    float s = 0.f;
    for (int r = t; r < NROWS; r += 256) {
        const float m = funkey(rowmax[r]);
        s += logf(2.0f - 2.0f * m + 1e-8f);
    }
#pragma unroll
    for (int off = 32; off > 0; off >>= 1) s += __shfl_xor(s, off);
    __shared__ float ws[4];
    if ((t & 63) == 0) ws[t >> 6] = s;
    __syncthreads();
    if (t == 0) out[0] = -0.5f * (ws[0] + ws[1] + ws[2] + ws[3]) / (float)NROWS;
}

extern "C" void kernel_launch(void* const* d_in, const int* in_sizes, int n_in,
                              void* d_out, int out_size, void* d_ws, size_t ws_size,
                              hipStream_t stream) {
    const float* x = (const float*)d_in[0];
    __hip_bfloat16* xn = (__hip_bfloat16*)d_ws;
    unsigned* rowmax = (unsigned*)((char*)d_ws + (size_t)NROWS * DIM * sizeof(__hip_bfloat16));
    float* out = (float*)d_out;

    normalize_rows<<<NROWS, 256, 0, stream>>>(x, xn, rowmax);
    dim3 grid(NROWS / 128, NROWS / 128);
    simmax_kernel<<<grid, 256, 0, stream>>>(xn, rowmax);
    finalize_kernel<<<1, 256, 0, stream>>>(rowmax, out);
}